// Round 5
// baseline (166.760 us; speedup 1.0000x reference)
//
#include <hip/hip_runtime.h>
#include <hip/hip_bf16.h>

#define BATCH 256
#define SEQ   512
#define NT    64
#define PCH   12    // chunks per sequence
#define CLEN  43    // steps per chunk: 11*43=473, last chunk 38 -> 511 total
#define PITCH 68    // ldsT pitch in halves (final transpose only)

typedef __attribute__((ext_vector_type(8)))  short bf16x8;
typedef __attribute__((ext_vector_type(16))) float f32x16;
typedef __attribute__((ext_vector_type(4)))  float f32x4;

#define MEMBAR() __asm__ __volatile__("" ::: "memory")

static __device__ __forceinline__ short bf16_trunc(float v) {
    return (short)(__float_as_uint(v) >> 16);
}
static __device__ __forceinline__ unsigned pack_bf16_rn(float lo, float hi) {
    float2 f; f.x = lo; f.y = hi;
    __hip_bfloat162 h = __float22bfloat162_rn(f);   // v_cvt_pk_bf16_f32
    unsigned u; __builtin_memcpy(&u, &h, 4);
    return u;
}

// ---------------------------------------------------------------------------
// Chunk kernel: one wave per (batch, chunk). Register-resident matrix chain
// (C accs feed next step's B operands; row permutation pre-folded into A).
// Also computes this chunk's slice of the gold-path numerator (distributed).
// ---------------------------------------------------------------------------
__global__ __launch_bounds__(64, 2) void crf_chunk_kernel(
    const float* __restrict__ emissions,   // (B,S,T)
    const int*   __restrict__ tags,        // (B,S)
    const int*   __restrict__ mask,        // (B,S)
    const float* __restrict__ start_tr,    // (T)
    const float* __restrict__ trans,       // (T,T)
    unsigned short* __restrict__ mats,     // (B,PCH,64,64) bf16: [n][k] = M[k][n]
    float* __restrict__ ws_head,           // [0]=sum, [1]=cnt (zero-init here)
    float* __restrict__ score_part,        // (B,PCH) numerator partials
    int*   __restrict__ mcnt_part)         // (B,PCH) mask-count partials
{
    __shared__ __align__(16) unsigned char smem[CLEN * NT * 4];  // 11 KB
    float (*w_lds)[NT] = (float (*)[NT])smem;
    unsigned short* ldsT = (unsigned short*)smem;

    const int c    = blockIdx.x;
    const int b    = blockIdx.y;
    const int lane = threadIdx.x;
    const int h    = lane >> 5;
    const int ml   = lane & 31;

    if (c == 0 && b == 0 && lane == 0) {
        ws_head[0] = 0.f;
        ((unsigned*)ws_head)[1] = 0u;
    }

    const int s0 = c * CLEN;
    int L = (SEQ - 1) - s0; if (L > CLEN) L = CLEN;

    const float* em_b = emissions + (size_t)b * SEQ * NT;
    const int*   tg_b = tags + b * SEQ;
    const int*   mk_b = mask + b * SEQ;

    for (int s = 0; s < L; ++s)
        w_lds[s][lane] = __expf(em_b[(size_t)(s0 + 1 + s) * NT + lane]);

    // ---- distributed numerator partial: steps s in [s0+1, s0+L] ----
    float np = 0.f;
    int   mc = 0;
    if (lane < L) {
        int s  = s0 + 1 + lane;
        int m  = mk_b[s];
        mc = m;
        int t  = tg_b[s];
        int tp = tg_b[s - 1];
        float v = trans[tp * NT + t] + em_b[(size_t)s * NT + t];
        np = m ? v : 0.f;
    }
    if (c == 0 && lane == 0) {
        int t0 = tg_b[0];
        np += start_tr[t0] + em_b[t0];
        mc += mk_b[0];
    }
#pragma unroll
    for (int d = 32; d; d >>= 1) {
        np += __shfl_xor(np, d);
        mc += __shfl_xor(mc, d);
    }
    if (lane == 0) {
        score_part[b * PCH + c] = np;
        mcnt_part[b * PCH + c]  = mc;
    }

    // Permuted A: Af[mt][kk] slot (h,j) = Es[mt*32+ml][r], Es = E^T * 2^-7,
    // r = 32*(kk>>1) + 16*(kk&1) + (j&3) + 8*(j>>2) + 4h
    bf16x8 Af[2][4];
#pragma unroll
    for (int mt = 0; mt < 2; ++mt) {
        int m = mt * 32 + ml;
#pragma unroll
        for (int kk = 0; kk < 4; ++kk) {
            bf16x8 f;
#pragma unroll
            for (int j = 0; j < 8; ++j) {
                int r = 32 * (kk >> 1) + 16 * (kk & 1) + (j & 3) + 8 * (j >> 2) + 4 * h;
                f[j] = bf16_trunc(__expf(trans[r * NT + m]) * 0.0078125f);
            }
            Af[mt][kk] = f;
        }
    }

    // B := identity (permuted-B register convention)
    union BU { unsigned u[4]; bf16x8 v; };
    BU Bv[4][2];
#pragma unroll
    for (int kk = 0; kk < 4; ++kk)
#pragma unroll
        for (int nt = 0; nt < 2; ++nt) {
            int n = nt * 32 + ml;
#pragma unroll
            for (int d = 0; d < 4; ++d) {
                int j0 = 2 * d;
                int r0 = 32 * (kk >> 1) + 16 * (kk & 1) + (j0 & 3) + 8 * (j0 >> 2) + 4 * h;
                unsigned lo = (r0     == n) ? 0x3f80u : 0u;
                unsigned hi = (r0 + 1 == n) ? 0x3f80u : 0u;
                Bv[kk][nt].u[d] = lo | (hi << 16);
            }
        }

    __syncthreads();  // w_lds drained (single wave: waitcnt only)

    const f32x16 zf = {};

    for (int s = 0; s < L; ++s) {
        f32x4 wq[4][2];
#pragma unroll
        for (int kk = 0; kk < 4; ++kk) {
            int base = 32 * (kk >> 1) + 16 * (kk & 1) + 4 * h;
            wq[kk][0] = *(const f32x4*)&w_lds[s][base];
            wq[kk][1] = *(const f32x4*)&w_lds[s][base + 8];
        }

        f32x16 acc[2][2];
#pragma unroll
        for (int mt = 0; mt < 2; ++mt)
#pragma unroll
            for (int nt = 0; nt < 2; ++nt) {
                f32x16 a = __builtin_amdgcn_mfma_f32_32x32x16_bf16(Af[mt][0], Bv[0][nt].v, zf, 0, 0, 0);
                a = __builtin_amdgcn_mfma_f32_32x32x16_bf16(Af[mt][1], Bv[1][nt].v, a, 0, 0, 0);
                a = __builtin_amdgcn_mfma_f32_32x32x16_bf16(Af[mt][2], Bv[2][nt].v, a, 0, 0, 0);
                a = __builtin_amdgcn_mfma_f32_32x32x16_bf16(Af[mt][3], Bv[3][nt].v, a, 0, 0, 0);
                acc[mt][nt] = a;
            }

        // Repack: B-slot (kk,nt,d) <- w[r]*C[r][n] pairs, packed cvt to bf16.
#pragma unroll
        for (int kk = 0; kk < 4; ++kk) {
            const int mt_s = kk >> 1, qo = 8 * (kk & 1);
#pragma unroll
            for (int nt = 0; nt < 2; ++nt) {
#pragma unroll
                for (int d = 0; d < 4; ++d) {
                    int j0 = 2 * d;
                    float v0 = acc[mt_s][nt][qo + j0]     * wq[kk][d >> 1][2 * (d & 1)];
                    float v1 = acc[mt_s][nt][qo + j0 + 1] * wq[kk][d >> 1][2 * (d & 1) + 1];
                    Bv[kk][nt].u[d] = pack_bf16_rn(v0, v1);
                }
            }
        }
    }

    // Transpose through LDS (once) -> mats[n][k] = M[k][n]
    __threadfence_block();
#pragma unroll
    for (int kk = 0; kk < 4; ++kk)
#pragma unroll
        for (int nt = 0; nt < 2; ++nt) {
            int n = nt * 32 + ml;
#pragma unroll
            for (int d = 0; d < 4; ++d) {
                int j0 = 2 * d;
                int r0 = 32 * (kk >> 1) + 16 * (kk & 1) + (j0 & 3) + 8 * (j0 >> 2) + 4 * h;
                *(unsigned*)&ldsT[n * PITCH + r0] = Bv[kk][nt].u[d];
            }
        }
    __threadfence_block();

    unsigned short* outp = mats + ((size_t)(b * PCH + c)) * 4096;
    for (int it = 0; it < 8; ++it) {
        int o = it * 512 + lane * 8;
        int n = o >> 6, k = o & 63;
        const uint2* p = (const uint2*)(ldsT + n * PITCH + k);
        uint2 x = p[0], y = p[1];
        uint4 q4; q4.x = x.x; q4.y = x.y; q4.z = y.x; q4.w = y.y;
        *(uint4*)(outp + o) = q4;
    }
}

// ---------------------------------------------------------------------------
// Combine: 1 wave per batch. 12-step matvec chain, distance-2 prefetch,
// compiler-barrier-only LDS round-trips (no vmcnt(0) drain -> prefetch lives).
// ---------------------------------------------------------------------------
__global__ __launch_bounds__(64) void crf_combine_kernel(
    const float* __restrict__ emissions,
    const int*   __restrict__ tags,
    const float* __restrict__ start_tr,
    const float* __restrict__ end_tr,
    const unsigned short* __restrict__ mats,
    const float* __restrict__ score_part,
    const int*   __restrict__ mcnt_part,
    float* __restrict__ ws_head,
    float* __restrict__ out)
{
    __shared__ __align__(16) float r_lds[NT];

    const int b = blockIdx.x;
    const int j = threadIdx.x;

    const float* em_b = emissions + (size_t)b * SEQ * NT;
    const int*   tg_b = tags + b * SEQ;
    const unsigned short* mb = mats + (size_t)b * PCH * 4096;

    // numerator partials (loads fly while chain starts)
    float sp = (j < PCH) ? score_part[b * PCH + j] : 0.f;
    int   mp = (j < PCH) ? mcnt_part[b * PCH + j] : 0;

    float r = __expf(end_tr[j]);
    r_lds[j] = r;
    MEMBAR();
    int X = 0;

    uint4 buf[3][8];
#pragma unroll
    for (int u = 0; u < 8; ++u)
        buf[0][u] = *(const uint4*)(mb + (size_t)(PCH - 1) * 4096 + j * 64 + u * 8);
#pragma unroll
    for (int u = 0; u < 8; ++u)
        buf[1][u] = *(const uint4*)(mb + (size_t)(PCH - 2) * 4096 + j * 64 + u * 8);

#pragma unroll
    for (int d = 32; d; d >>= 1) {
        sp += __shfl_xor(sp, d);
        mp += __shfl_xor(mp, d);
    }
    int last_tag = tg_b[mp - 1];          // same addr all lanes
    float score_num = sp + end_tr[last_tag];

#pragma unroll
    for (int c = PCH - 1; c >= 0; --c) {
        const int slot  = (PCH - 1 - c) % 3;
        const int nslot = (PCH - 1 - c + 2) % 3;
        if (c >= 2) {
#pragma unroll
            for (int u = 0; u < 8; ++u)
                buf[nslot][u] = *(const uint4*)(mb + (size_t)(c - 2) * 4096 + j * 64 + u * 8);
        }
        float a0 = 0.f, a1 = 0.f, a2 = 0.f, a3 = 0.f;
#pragma unroll
        for (int u = 0; u < 8; ++u) {
            uint4 q = buf[slot][u];
            f32x4 ra = *(const f32x4*)&r_lds[u * 8];
            f32x4 rb = *(const f32x4*)&r_lds[u * 8 + 4];
            a0 = fmaf(ra[0], __uint_as_float(q.x << 16),         a0);
            a1 = fmaf(ra[1], __uint_as_float(q.x & 0xffff0000u), a1);
            a2 = fmaf(ra[2], __uint_as_float(q.y << 16),         a2);
            a3 = fmaf(ra[3], __uint_as_float(q.y & 0xffff0000u), a3);
            a0 = fmaf(rb[0], __uint_as_float(q.z << 16),         a0);
            a1 = fmaf(rb[1], __uint_as_float(q.z & 0xffff0000u), a1);
            a2 = fmaf(rb[2], __uint_as_float(q.w << 16),         a2);
            a3 = fmaf(rb[3], __uint_as_float(q.w & 0xffff0000u), a3);
        }
        float rn = (a0 + a1) + (a2 + a3);
        unsigned eb = (__builtin_amdgcn_readfirstlane((int)__float_as_uint(rn)) >> 23) & 0xffu;
        r = rn * __uint_as_float((254u - eb) << 23);   // * 2^(127-eb)
        X += (int)eb - 127;
        MEMBAR();
        r_lds[j] = r;     // in-order LDS pipe: prior reads already issued
        MEMBAR();
    }

    float u0 = __expf(start_tr[j] + em_b[j]);
    float v = r * u0;
#pragma unroll
    for (int d = 32; d; d >>= 1) v += __shfl_xor(v, d);

    if (j == 0) {
        float denom = __logf(v) + (float)(X + 7 * (SEQ - 1)) * 0.6931471805599453f;
        float llh = denom - score_num;
        atomicAdd(&ws_head[0], llh * (1.0f / BATCH));
        __threadfence();
        unsigned old = atomicAdd((unsigned*)ws_head + 1, 1u);
        if (old == BATCH - 1) {
            __threadfence();
            out[0] = atomicAdd(&ws_head[0], 0.0f);
        }
    }
}

extern "C" void kernel_launch(void* const* d_in, const int* in_sizes, int n_in,
                              void* d_out, int out_size, void* d_ws, size_t ws_size,
                              hipStream_t stream) {
    const float* emissions = (const float*)d_in[0];
    const int*   tags      = (const int*)d_in[1];
    const int*   mask      = (const int*)d_in[2];
    const float* start_tr  = (const float*)d_in[3];
    const float* end_tr    = (const float*)d_in[4];
    const float* trans     = (const float*)d_in[5];

    float* ws_head    = (float*)d_ws;
    float* score_part = (float*)((char*)d_ws + 64);
    int*   mcnt_part  = (int*)((char*)d_ws + 64 + 4 * BATCH * PCH);
    unsigned short* mats = (unsigned short*)((char*)d_ws + 32768);  // 24 MB bf16

    crf_chunk_kernel<<<dim3(PCH, BATCH), 64, 0, stream>>>(
        emissions, tags, mask, start_tr, trans, mats, ws_head, score_part, mcnt_part);
    crf_combine_kernel<<<BATCH, 64, 0, stream>>>(
        emissions, tags, start_tr, end_tr, mats, score_part, mcnt_part,
        ws_head, (float*)d_out);
}